// Round 1
// baseline (61.446 us; speedup 1.0000x reference)
//
#include <hip/hip_runtime.h>
#include <hip/hip_bf16.h>

typedef float  f32x4 __attribute__((ext_vector_type(4)));
typedef short  s16x8 __attribute__((ext_vector_type(8)));
typedef __bf16 b16x8 __attribute__((ext_vector_type(8)));
typedef __bf16 b16x2 __attribute__((ext_vector_type(2)));

#define NROWS 8192
#define ROWP  72   // padded row length (shorts) for transposed-T tile; 144 B = 16-aligned

__device__ __forceinline__ f32x4 mfma_bf16(s16x8 a, s16x8 b, f32x4 c) {
    return __builtin_amdgcn_mfma_f32_16x16x32_bf16(
        __builtin_bit_cast(b16x8, a), __builtin_bit_cast(b16x8, b), c, 0, 0, 0);
}

__device__ __forceinline__ short f2b(float f) {
    return __builtin_bit_cast(short, (__bf16)f);
}

// Load 8 contiguous fp32 from a 64x64 row-major matrix -> bf16x8 fragment sliver.
// lane -> row = rbase, cols cbase..cbase+7
__device__ __forceinline__ s16x8 load_frag64(const float* __restrict__ mat, int row, int colbase) {
    const float* p = mat + row * 64 + colbase;
    f32x4 a = *reinterpret_cast<const f32x4*>(p);
    f32x4 b = *reinterpret_cast<const f32x4*>(p + 4);
    s16x8 r;
    r[0] = f2b(a[0]); r[1] = f2b(a[1]); r[2] = f2b(a[2]); r[3] = f2b(a[3]);
    r[4] = f2b(b[0]); r[5] = f2b(b[1]); r[6] = f2b(b[2]); r[7] = f2b(b[3]);
    return r;
}

// Per row n: Out = W1 (64x64) * X (64x64) * W2^T (64x64)
// Stage 1: T = X @ W2^T   (A-frag = X direct from global, B-frag = W2 rows)
// Stage 2: Out = W1 @ T   (A-frag = W1, B-frag = T via LDS transpose round-trip)
__global__ __launch_bounds__(256) void kron2_kernel(
    const float* __restrict__ data, const float* __restrict__ W1,
    const float* __restrict__ W2, float* __restrict__ out)
{
    __shared__ short lds[4][64][ROWP];   // per-wave transposed T: Ttr[col][row]
    const int lane = threadIdx.x & 63;
    const int wv   = threadIdx.x >> 6;
    const int c    = lane & 15;          // MFMA row/col index within 16-tile
    const int g    = lane >> 4;          // k-group (0..3)
    short (*T)[ROWP] = lds[wv];

    // Persistent weight fragments.
    // Stage-1 B (W2^T in KxN form): lane holds W2T[k, col] = W2[col, k] -> read W2 rows.
    // Stage-2 A (W1 in MxK form):   lane holds W1[row, k]               -> read W1 rows.
    s16x8 w2f[4][2], w1f[4][2];
    #pragma unroll
    for (int t = 0; t < 4; ++t)
      #pragma unroll
      for (int kh = 0; kh < 2; ++kh) {
        w2f[t][kh] = load_frag64(W2, t * 16 + c, kh * 32 + g * 8);
        w1f[t][kh] = load_frag64(W1, t * 16 + c, kh * 32 + g * 8);
      }

    const int wgid = (int)((blockIdx.x * blockDim.x + threadIdx.x) >> 6);
    const int nw   = (int)((gridDim.x * blockDim.x) >> 6);

    for (int n = wgid; n < NROWS; n += nw) {
        const float* X = data + (size_t)n * 4096;

        // ---- stage 1: T = X @ W2^T ; write T transposed into LDS ----
        #pragma unroll
        for (int mt = 0; mt < 4; ++mt) {
            s16x8 xa0 = load_frag64(X, mt * 16 + c, 0 * 32 + g * 8);
            s16x8 xa1 = load_frag64(X, mt * 16 + c, 1 * 32 + g * 8);
            #pragma unroll
            for (int nt = 0; nt < 4; ++nt) {
                f32x4 acc = {0.f, 0.f, 0.f, 0.f};
                acc = mfma_bf16(xa0, w2f[nt][0], acc);
                acc = mfma_bf16(xa1, w2f[nt][1], acc);
                // lane holds T[mt*16 + g*4 + r][nt*16 + c], r=0..3 (verified C/D layout)
                b16x2 p0; p0[0] = (__bf16)acc[0]; p0[1] = (__bf16)acc[1];
                b16x2 p1; p1[0] = (__bf16)acc[2]; p1[1] = (__bf16)acc[3];
                int2 v;
                v.x = __builtin_bit_cast(int, p0);
                v.y = __builtin_bit_cast(int, p1);
                *reinterpret_cast<int2*>(&T[nt * 16 + c][mt * 16 + g * 4]) = v;
            }
        }

        // ---- stage 2: Out = W1 @ T ----
        // B-frag: lane holds T[k, col] = Ttr[col][k], 8 contiguous k -> ds_read_b128
        s16x8 tf[4][2];
        #pragma unroll
        for (int nt = 0; nt < 4; ++nt)
          #pragma unroll
          for (int kh = 0; kh < 2; ++kh)
            tf[nt][kh] = *reinterpret_cast<const s16x8*>(&T[nt * 16 + c][kh * 32 + g * 8]);

        #pragma unroll
        for (int mt = 0; mt < 4; ++mt) {
            float* O = out + (size_t)n * 4096 + (mt * 16 + g * 4) * 64 + c;
            #pragma unroll
            for (int nt = 0; nt < 4; ++nt) {
                f32x4 acc = {0.f, 0.f, 0.f, 0.f};
                acc = mfma_bf16(w1f[mt][0], tf[nt][0], acc);
                acc = mfma_bf16(w1f[mt][1], tf[nt][1], acc);
                #pragma unroll
                for (int r = 0; r < 4; ++r)
                    O[nt * 16 + r * 64] = acc[r];   // 64B-contiguous across lanes 0..15
            }
        }
    }
}

extern "C" void kernel_launch(void* const* d_in, const int* in_sizes, int n_in,
                              void* d_out, int out_size, void* d_ws, size_t ws_size,
                              hipStream_t stream) {
    const float* data = (const float*)d_in[0];
    const float* W1   = (const float*)d_in[1];
    const float* W2   = (const float*)d_in[2];
    float* out        = (float*)d_out;
    dim3 grid(1024), block(256);   // 4096 waves, 2 rows per wave
    hipLaunchKernelGGL(kron2_kernel, grid, block, 0, stream, data, W1, W2, out);
}